// Round 11
// baseline (168.005 us; speedup 1.0000x reference)
//
#include <hip/hip_runtime.h>

#define HW 4096
#define LCAP 1536      // per-block hit list (expected ~80/block)

typedef short bf16x8 __attribute__((ext_vector_type(8)));
typedef float f32x16 __attribute__((ext_vector_type(16)));

__device__ __forceinline__ ushort f2bf_rne(float f) {
    unsigned u = __float_as_uint(f);
    return (ushort)((u + 0x7FFFu + ((u >> 16) & 1u)) >> 16);
}

// ---------------------------------------------------------------------------
// W transpose: Wt[c][o] = W[o][c].
// ---------------------------------------------------------------------------
__global__ __launch_bounds__(256) void transpose_w_kernel(
    const float* __restrict__ Wm, float* __restrict__ Wt)
{
    const int o = blockIdx.x;        // 128
    const int c = threadIdx.x;       // 256
    Wt[c * 128 + o] = Wm[o * 256 + c];
}

// ---------------------------------------------------------------------------
// Kernel 1: 1x1-conv projection (v1 structure + named-register prefetch).
// R10: grid 512 = 2 blocks/CU -> barriers exposed staging latency (Occ 16%,
// VALU 37%).  Prefetch chunk cc+1 into NAMED float4 regs (w0..w7,x0..x3;
// R7's array prefetch on the 8x8 tile spilled - acc here is 32 regs, total
// ~95, no spill) issued after the post-stage barrier -> latency hides under
// the 64-r FMA block.  Accumulation order unchanged -> Qt/Pt/Ppk bitwise
// identical.  R10 scale-fold: Qpk now packs bf16(256*q/||q||) (error budget
// in code units identical: 2*2^-9*||256qhat||*||phat|| = 1.0 code), so sim
// needs no per-n scale.  qnorm is GONE from the whole pipeline.
// PK[b][t32][ks][lt][j] = proj[c=ks*16+(lt>>5)*8+j][n=t32*32+(lt&31)].
// ---------------------------------------------------------------------------
__global__ __launch_bounds__(256) void proj_kernel(
    const float* __restrict__ Fq, const float* __restrict__ Fp,
    const float* __restrict__ Wt, const float* __restrict__ bias,
    float* __restrict__ Qt, float* __restrict__ Pt,
    ushort* __restrict__ Qpk, ushort* __restrict__ Ppk)
{
    __shared__ float Ws[64][128];    // 32 KB: c-chunk x o
    __shared__ float Xs[64][64];     // 16 KB: c-chunk x n
    __shared__ float psum[16][68];   // padded norm partials

    const int tid = threadIdx.x;
    const int z  = blockIdx.z;                 // 0: q, 1: p
    const float* __restrict__ X = z ? Fp : Fq;
    const int b  = blockIdx.y;
    const int n0 = blockIdx.x * 64;
    const int og = tid >> 4;                   // 0..15 -> o = og*8 .. +8
    const int ng = tid & 15;                   // 0..15 -> n = n0+ng*4 .. +4

    float acc[4][8];                           // [n][o]
    #pragma unroll
    for (int i = 0; i < 4; ++i)
        #pragma unroll
        for (int j = 0; j < 8; ++j) acc[i][j] = 0.f;

    // named prefetch registers (rule-#20-proof: no arrays)
    float4 w0, w1, w2, w3, w4, w5, w6, w7;
    float4 x0, x1, x2, x3;
    const int xr0 = tid >> 4,            xn0 = (tid & 15) * 4;          // it=0
    const int xr1 = (256 + tid) >> 4,    xn1 = xn0;                     // it=1
    const int xr2 = (512 + tid) >> 4,    xn2 = xn0;                     // it=2
    const int xr3 = (768 + tid) >> 4,    xn3 = xn0;                     // it=3

#define LOAD_CHUNK(cc_)                                                        \
    {                                                                          \
        const float4* s_ = (const float4*)(Wt + (size_t)(cc_) * 64 * 128);     \
        w0 = s_[0 * 256 + tid]; w1 = s_[1 * 256 + tid];                        \
        w2 = s_[2 * 256 + tid]; w3 = s_[3 * 256 + tid];                        \
        w4 = s_[4 * 256 + tid]; w5 = s_[5 * 256 + tid];                        \
        w6 = s_[6 * 256 + tid]; w7 = s_[7 * 256 + tid];                        \
        const size_t cb_ = (size_t)(b * 256 + (cc_) * 64);                     \
        x0 = *(const float4*)&X[(cb_ + xr0) * HW + n0 + xn0];                  \
        x1 = *(const float4*)&X[(cb_ + xr1) * HW + n0 + xn1];                  \
        x2 = *(const float4*)&X[(cb_ + xr2) * HW + n0 + xn2];                  \
        x3 = *(const float4*)&X[(cb_ + xr3) * HW + n0 + xn3];                  \
    }

    LOAD_CHUNK(0);

    for (int cc = 0; cc < 4; ++cc) {
        __syncthreads();                       // prior chunk's reads done
        {
            float4* dst = (float4*)Ws;
            dst[0 * 256 + tid] = w0; dst[1 * 256 + tid] = w1;
            dst[2 * 256 + tid] = w2; dst[3 * 256 + tid] = w3;
            dst[4 * 256 + tid] = w4; dst[5 * 256 + tid] = w5;
            dst[6 * 256 + tid] = w6; dst[7 * 256 + tid] = w7;
        }
        *(float4*)&Xs[xr0][xn0] = x0;
        *(float4*)&Xs[xr1][xn1] = x1;
        *(float4*)&Xs[xr2][xn2] = x2;
        *(float4*)&Xs[xr3][xn3] = x3;
        __syncthreads();

        if (cc < 3) LOAD_CHUNK(cc + 1);        // completes under the FMAs

        for (int r = 0; r < 64; ++r) {
            float4 a0 = *(const float4*)&Ws[r][og * 8];
            float4 a1 = *(const float4*)&Ws[r][og * 8 + 4];
            float4 xv = *(const float4*)&Xs[r][ng * 4];
            float wa[8] = {a0.x, a0.y, a0.z, a0.w, a1.x, a1.y, a1.z, a1.w};
            float xa[4] = {xv.x, xv.y, xv.z, xv.w};
            #pragma unroll
            for (int i = 0; i < 4; ++i)
                #pragma unroll
                for (int j = 0; j < 8; ++j)
                    acc[i][j] += wa[j] * xa[i];
        }
    }
#undef LOAD_CHUNK

    {
        float4 b0 = *(const float4*)&bias[og * 8];
        float4 b1 = *(const float4*)&bias[og * 8 + 4];
        float ba[8] = {b0.x, b0.y, b0.z, b0.w, b1.x, b1.y, b1.z, b1.w};
        #pragma unroll
        for (int i = 0; i < 4; ++i)
            #pragma unroll
            for (int j = 0; j < 8; ++j) acc[i][j] += ba[j];
    }

    #pragma unroll
    for (int i = 0; i < 4; ++i) {
        float s = 0.f;
        #pragma unroll
        for (int j = 0; j < 8; ++j) s += acc[i][j] * acc[i][j];
        psum[og][ng * 4 + i] = s;
    }
    __syncthreads();
    float tot[4];
    #pragma unroll
    for (int i = 0; i < 4; ++i) {
        float s = 0.f;
        #pragma unroll
        for (int g = 0; g < 16; ++g) s += psum[g][ng * 4 + i];
        tot[i] = s;
    }

    float pscale[4];                 // pack scale: q -> 256/||q||, p -> 1
    if (z) {   // normalize p over its 128 channels (Pt and Ppk both p-hat)
        #pragma unroll
        for (int i = 0; i < 4; ++i) {
            float s = 1.0f / sqrtf(tot[i]);
            #pragma unroll
            for (int j = 0; j < 8; ++j) acc[i][j] *= s;
            pscale[i] = 1.0f;
        }
    } else {
        #pragma unroll
        for (int i = 0; i < 4; ++i) pscale[i] = 256.0f / sqrtf(tot[i]);
    }

    {
        float* __restrict__ T = z ? Pt : Qt;   // Qt raw, Pt normalized
        #pragma unroll
        for (int i = 0; i < 4; ++i) {
            size_t tb = ((size_t)b * HW + n0 + ng * 4 + i) * 128 + og * 8;
            *(float4*)&T[tb]     = make_float4(acc[i][0], acc[i][1], acc[i][2], acc[i][3]);
            *(float4*)&T[tb + 4] = make_float4(acc[i][4], acc[i][5], acc[i][6], acc[i][7]);
        }
    }
    {
        ushort* __restrict__ PK = z ? Ppk : Qpk;
        const int ks = og >> 1;
        #pragma unroll
        for (int i = 0; i < 4; ++i) {
            const int na  = n0 + ng * 4 + i;
            const int t32 = na >> 5;
            const int lt  = (na & 31) + 32 * (og & 1);
            ushort u[8];
            #pragma unroll
            for (int k = 0; k < 8; ++k) u[k] = f2bf_rne(acc[i][k] * pscale[i]);
            size_t pk = ((((size_t)b * 128 + t32) * 8 + ks) * 64 + lt) * 8;
            uint4 w;
            w.x = (unsigned)u[0] | ((unsigned)u[1] << 16);
            w.y = (unsigned)u[2] | ((unsigned)u[3] << 16);
            w.z = (unsigned)u[4] | ((unsigned)u[5] << 16);
            w.w = (unsigned)u[6] | ((unsigned)u[7] << 16);
            *(uint4*)&PK[pk] = w;
        }
    }
}

// ---------------------------------------------------------------------------
// SINGLE sim pass: staged-B + register-Q + BM sidecar.  R10: Qpk is already
// scaled by 256/||q|| (proj scale-fold), so codes = cvt(acc) DIRECTLY: the
// 16 rq loads + 16 muls/tile are gone.  SK/BM stay mutually bitwise-
// consistent (both derive from the same acc; cvt monotone; shuffle-max exact).
// ---------------------------------------------------------------------------
__global__ __launch_bounds__(256, 4) void sim_sketch_kernel(
    const ushort* __restrict__ Qpk, const ushort* __restrict__ Ppk,
    unsigned char* __restrict__ SK, unsigned char* __restrict__ BM)
{
    __shared__ ushort Bs[16384];   // 32 KB: 4 t32-rows of Ppk

    const int tid  = threadIdx.x;
    const int lane = tid & 63;
    const int w    = tid >> 6;
    const int nb   = blockIdx.x;
    const int b    = blockIdx.y;
    const int ms   = blockIdx.z;               // 0..31, 128 m's each
    const int hi   = lane >> 5;

    // stage B: t32-rows ms*4..+4 (32 KB), cooperative, coalesced
    {
        const uint4* src = (const uint4*)(Ppk + ((size_t)(b * 128 + ms * 4)) * 4096);
        uint4* dst = (uint4*)Bs;
        #pragma unroll
        for (int it = 0; it < 8; ++it) dst[it * 256 + tid] = src[it * 256 + tid];
    }

    // Q fragments: 8 x bf16x8 (32 VGPRs), loaded once, coalesced (L2-hit)
    const ushort* __restrict__ qbase =
        Qpk + ((size_t)(b * 128 + nb * 4)) * 4096 + (size_t)lane * 8;
    bf16x8 qf[8];
    #pragma unroll
    for (int ks = 0; ks < 8; ++ks)
        qf[ks] = *(const bf16x8*)(qbase + (w * 8 + ks) * 512);

    const size_t g16f = (size_t)b * 256 + (size_t)(nb * 4 + w) * 2 + hi;
    const int mb0 = ms * 128 + (lane & 31);

    float xmax[16];
    #pragma unroll
    for (int r = 0; r < 16; ++r) xmax[r] = -1e30f;

    __syncthreads();   // Bs ready

    #pragma unroll 2
    for (int mtl = 0; mtl < 4; ++mtl) {
        f32x16 acc;
        #pragma unroll
        for (int r = 0; r < 16; ++r) acc[r] = 0.f;
        #pragma unroll
        for (int ks = 0; ks < 8; ++ks) {
            bf16x8 bb = *(const bf16x8*)&Bs[((mtl * 8 + ks) * 64 + lane) * 8];
            acc = __builtin_amdgcn_mfma_f32_32x32x16_bf16(qf[ks], bb, acc, 0, 0, 0);
        }

        // quantize: acc is already in code units (256 * cos)
        unsigned dw[4] = {0u, 0u, 0u, 0u};
        #pragma unroll
        for (int r = 0; r < 16; ++r) {
            float x = acc[r];
            xmax[r] = fmaxf(xmax[r], x);
#if __has_builtin(__builtin_amdgcn_cvt_pk_u8_f32)
            dw[r >> 2] = (unsigned)__builtin_amdgcn_cvt_pk_u8_f32(
                x, (unsigned)(r & 3), (int)dw[r >> 2]);
#else
            int vi = (int)rintf(x);
            vi = vi < 0 ? 0 : (vi > 255 ? 255 : vi);
            dw[r >> 2] |= (unsigned)vi << (8 * (r & 3));
#endif
        }
        const int m = mb0 + mtl * 32;
        uint4 pk;
        pk.x = dw[0]; pk.y = dw[1]; pk.z = dw[2]; pk.w = dw[3];
        *(uint4*)(SK + ((g16f * 4096 + (size_t)m) << 4)) = pk;
    }

    // cross-lane (32 m's) exact fp32 max, then the SAME cvt as the codes ->
    // BM byte == max of the 128 SK bytes it summarizes, bitwise.
    #pragma unroll
    for (int r = 0; r < 16; ++r) {
        float v = xmax[r];
        #pragma unroll
        for (int d = 1; d < 32; d <<= 1)
            v = fmaxf(v, __shfl_xor(v, d, 64));
        xmax[r] = v;
    }
    if ((lane & 31) == 0) {
        unsigned dw[4] = {0u, 0u, 0u, 0u};
        #pragma unroll
        for (int r = 0; r < 16; ++r) {
#if __has_builtin(__builtin_amdgcn_cvt_pk_u8_f32)
            dw[r >> 2] = (unsigned)__builtin_amdgcn_cvt_pk_u8_f32(
                xmax[r], (unsigned)(r & 3), (int)dw[r >> 2]);
#else
            int vi = (int)rintf(xmax[r]);
            vi = vi < 0 ? 0 : (vi > 255 ? 255 : vi);
            dw[r >> 2] |= (unsigned)vi << (8 * (r & 3));
#endif
        }
        uint4 pk;
        pk.x = dw[0]; pk.y = dw[1]; pk.z = dw[2]; pk.w = dw[3];
        *(uint4*)(BM + ((g16f * 32 + (size_t)ms) << 4)) = pk;
    }
}

// ---------------------------------------------------------------------------
// fused init + threshold-from-BM + SWAR scan + exact fp32 rescore (frozen
// from R9).  t8[n] = maxcode[n] - 6; cushion: per-side error <= 1.0 code
// (bf16 operand rounding) + 0.5 (rne) -> 2 sides ~3.0 < 6 => the true fp32
// argmax always survives; false hits killed by exact rescore.
// SWAR gate: GE_msb(x,y) = ((x&~y) | (~(x^y) & ((x|H)-(y&~H)))) & H.
// ---------------------------------------------------------------------------
__device__ __noinline__ void dot_one_slow(
    const float* Qsrow, const float* __restrict__ Pt,
    int b, int m, int n, unsigned long long* __restrict__ best)
{
    const float4* __restrict__ pr = (const float4*)&Pt[((size_t)b * HW + m) * 128];
    float acc = 0.f;
    #pragma unroll
    for (int k = 0; k < 32; ++k) {
        float4 pv = pr[k];
        float4 qv = *(const float4*)&Qsrow[k * 4];
        acc += qv.x * pv.x + qv.y * pv.y + qv.z * pv.z + qv.w * pv.w;
    }
    unsigned u = __float_as_uint(acc);
    unsigned kk = (u & 0x80000000u) ? ~u : (u | 0x80000000u);
    unsigned long long key = ((unsigned long long)kk << 32) | (unsigned)(4095 - m);
    atomicMax(&best[(size_t)b * HW + n], key);
}

__global__ __launch_bounds__(256) void scan_rescore_kernel(
    const unsigned char* __restrict__ SK, const unsigned char* __restrict__ BM,
    const float* __restrict__ Qt, const float* __restrict__ Pt,
    unsigned long long* __restrict__ best)
{
    __shared__ float Qs[16][132];
    __shared__ int nlist[16];
    __shared__ int t8s[16];
    __shared__ ushort hl[LCAP];
    __shared__ unsigned lcnt;

    const int fg  = blockIdx.x;               // b*256 + g16
    const int tid = threadIdx.x;
    const int b = fg >> 8, g = fg & 255, t = g >> 1, gs = g & 1;

    if (tid == 0) lcnt = 0u;
    if (tid < 16) {
        int n = t * 32 + (tid & 3) + 8 * (tid >> 2) + 4 * gs;
        nlist[tid] = n;
        best[(size_t)b * HW + n] = 0ull;      // folded init: block-exclusive n
        const unsigned char* __restrict__ bmrow = BM + ((size_t)fg << 9);
        int mc = 0;
        #pragma unroll
        for (int ms = 0; ms < 32; ++ms)
            mc = max(mc, (int)bmrow[ms * 16 + tid]);
        int tt = mc - 6;
        t8s[tid] = tt < 0 ? 0 : tt;
    }
    __syncthreads();

    #pragma unroll
    for (int it = 0; it < 2; ++it) {
        int idx = it * 256 + tid;
        int row = idx >> 5, c4 = (idx & 31) * 4;
        *(float4*)&Qs[row][c4] =
            *(const float4*)&Qt[((size_t)b * HW + nlist[row]) * 128 + c4];
    }

    int myt[16];
    #pragma unroll
    for (int j = 0; j < 16; ++j) myt[j] = t8s[j];
    unsigned tw[4];
    #pragma unroll
    for (int d = 0; d < 4; ++d)
        tw[d] = (unsigned)myt[d * 4]
              | ((unsigned)myt[d * 4 + 1] << 8)
              | ((unsigned)myt[d * 4 + 2] << 16)
              | ((unsigned)myt[d * 4 + 3] << 24);
    __syncthreads();   // Qs staged (inline-overflow dots read it)

    const uint4* __restrict__ skrow = (const uint4*)(SK + ((size_t)fg << 16));
    const unsigned H = 0x80808080u;

    #pragma unroll 4
    for (int it = 0; it < 16; ++it) {
        const int m = it * 256 + tid;
        uint4 v = skrow[it * 256 + tid];
        unsigned wv[4] = {v.x, v.y, v.z, v.w};
        unsigned ge[4];
        #pragma unroll
        for (int d = 0; d < 4; ++d) {
            unsigned x = wv[d], y = tw[d];
            unsigned L = (x | H) - (y & ~H);
            ge[d] = ((x & ~y) | (~(x ^ y) & L)) & H;
        }
        if (ge[0] | ge[1] | ge[2] | ge[3]) {
            #pragma unroll
            for (int d = 0; d < 4; ++d) {
                if (ge[d]) {
                    #pragma unroll
                    for (int k = 0; k < 4; ++k) {
                        if (ge[d] & (0x80u << (8 * k))) {
                            int j = d * 4 + k;
                            unsigned pos = atomicAdd(&lcnt, 1u);
                            if (pos < LCAP) {
                                hl[pos] = (ushort)((j << 12) | m);
                            } else {   // overflow: inline (rare/never)
                                dot_one_slow(&Qs[j][0], Pt, b, m, nlist[j], best);
                            }
                        }
                    }
                }
            }
        }
    }

    __syncthreads();
    unsigned cnt = lcnt < LCAP ? lcnt : LCAP;
    for (unsigned p = tid; p < cnt; p += 256) {
        int e = hl[p];
        int j = e >> 12, m = e & 4095;
        const float4* __restrict__ pr = (const float4*)&Pt[((size_t)b * HW + m) * 128];
        float acc = 0.f;
        #pragma unroll
        for (int k = 0; k < 32; ++k) {
            float4 pv = pr[k];
            float4 qv = *(const float4*)&Qs[j][k * 4];
            acc += qv.x * pv.x + qv.y * pv.y + qv.z * pv.z + qv.w * pv.w;
        }
        unsigned u = __float_as_uint(acc);
        unsigned kk = (u & 0x80000000u) ? ~u : (u | 0x80000000u);
        unsigned long long key = ((unsigned long long)kk << 32) | (unsigned)(4095 - m);
        atomicMax(&best[(size_t)b * HW + nlist[j]], key);
    }
}

// ---------------------------------------------------------------------------
// gather: out[b][c][n] = Fp[b][c][m(n)]; stage each 16 KB Fp row in LDS.
// ---------------------------------------------------------------------------
__global__ __launch_bounds__(256) void gather_kernel(
    const float* __restrict__ Fp, const unsigned long long* __restrict__ best,
    float* __restrict__ out)
{
    __shared__ float row[4096];
    const int blk = blockIdx.x;      // 1024 = 4b x 256c
    const int c = blk & 255;
    const int b = blk >> 8;
    const int tid = threadIdx.x;

    const float* __restrict__ src = Fp + ((size_t)b * 256 + c) * HW;
    #pragma unroll
    for (int it = 0; it < 4; ++it) {
        int f = it * 256 + tid;
        *(float4*)&row[f * 4] = *(const float4*)&src[f * 4];
    }
    __syncthreads();

    float* __restrict__ dst = out + ((size_t)b * 256 + c) * HW;
    #pragma unroll
    for (int it = 0; it < 16; ++it) {
        int n = it * 256 + tid;
        int m = 4095 - (int)(best[(size_t)b * HW + n] & 0xFFFull);
        dst[n] = row[m];
    }
}

extern "C" void kernel_launch(void* const* d_in, const int* in_sizes, int n_in,
                              void* d_out, int out_size, void* d_ws, size_t ws_size,
                              hipStream_t stream) {
    const float* Fq   = (const float*)d_in[0];
    const float* Fp   = (const float*)d_in[1];
    const float* Wm   = (const float*)d_in[2];
    const float* bias = (const float*)d_in[3];
    float* out = (float*)d_out;

    char* base = (char*)d_ws;
    float*  Qt    = (float*)(base);                               // 8 MB
    float*  Pt    = (float*)(base + (8u << 20));                  // 8 MB
    ushort* Qpk   = (ushort*)(base + (16u << 20));                // 4 MB
    ushort* Ppk   = (ushort*)(base + (20u << 20));                // 4 MB
    unsigned char* SK = (unsigned char*)(base + (24u << 20));     // 64 MB
    char* x = base + (88u << 20);
    unsigned char* BM = (unsigned char*)x;  x += 524288;          // 512 KB
    unsigned long long* best = (unsigned long long*)x; x += 131072; // 128 KB
    float*  Wtg   = (float*)x;                                    // 128 KB

    transpose_w_kernel<<<128, 256, 0, stream>>>(Wm, Wtg);
    proj_kernel<<<dim3(64, 4, 2), 256, 0, stream>>>(Fq, Fp, Wtg, bias,
                                                    Qt, Pt, Qpk, Ppk);
    sim_sketch_kernel<<<dim3(32, 4, 32), 256, 0, stream>>>(Qpk, Ppk, SK, BM);
    scan_rescore_kernel<<<1024, 256, 0, stream>>>(SK, BM, Qt, Pt, best);
    gather_kernel<<<1024, 256, 0, stream>>>(Fp, best, out);
}